// Round 12
// baseline (225.579 us; speedup 1.0000x reference)
//
#include <hip/hip_runtime.h>
#include <math.h>

constexpr int kB  = 16;
constexpr int kS  = 256;
constexpr int kD  = 1024;
constexpr int kH  = 16;
constexpr float kScale = 0.125f;  // 1/sqrt(64)

using bf16x8  = __attribute__((ext_vector_type(8))) short;
using floatx4 = __attribute__((ext_vector_type(4))) float;
typedef unsigned short u16;

__device__ __forceinline__ u16 f2bf(float x) {
  union { float f; unsigned u; } v; v.f = x;
  unsigned r = v.u + 0x7fffu + ((v.u >> 16) & 1u);
  return (u16)(r >> 16);
}
__device__ __forceinline__ float bf2f(u16 h) {
  union { unsigned u; float f; } v; v.u = ((unsigned)h) << 16;
  return v.f;
}

#define MFMA16(a, b, c) __builtin_amdgcn_mfma_f32_16x16x32_bf16((a), (b), (c), 0, 0, 0)
#define GLL16(gp, lp)                                                        \
  __builtin_amdgcn_global_load_lds(                                          \
      (const __attribute__((address_space(1))) unsigned int*)(gp),           \
      (__attribute__((address_space(3))) unsigned int*)(lp), 16, 0, 0)

// ------- pack + table + uv-fold (merged): blocks <8451 pack, >=8451 fold -------
__global__ __launch_bounds__(256) void pack_k(
    const float* __restrict__ x, const float* __restrict__ Wq,
    const float* __restrict__ Wk, const float* __restrict__ Wv,
    const float* __restrict__ Wo,
    const float* __restrict__ bq, const float* __restrict__ bk,
    const float* __restrict__ bv,
    const float* __restrict__ Wr, const float* __restrict__ br,
    const float* __restrict__ ub, const float* __restrict__ vb,
    u16* __restrict__ xA, u16* __restrict__ W3b, u16* __restrict__ Wob,
    float* __restrict__ b3) {
  if (blockIdx.x >= 8451) {
    // ---- rank-16 fold of Wr with u/v: W3b rows 3072..3103, b3 tail ----
    int gid = (blockIdx.x - 8451) * 256 + threadIdx.x;  // 32768
    int j = gid >> 10, c = gid & 1023;
    int h = j & 15;
    const float* bvec = (j < 16 ? ub : vb) + h * 64;
    const float* wcol = Wr + (size_t)(h * 64) * 1024 + c;
    float a = 0.f;
#pragma unroll
    for (int d = 0; d < 64; ++d) a += bvec[d] * wcol[(size_t)d * 1024];
    W3b[(size_t)(3072 + j) * 1024 + c] = f2bf(a);
    if (gid < 128) {
      float s = 0.f;
      if (gid < 32) {
        const float* bv2 = (gid < 16 ? ub : vb) + (gid & 15) * 64;
        const float* brp = br + (gid & 15) * 64;
        for (int d = 0; d < 64; ++d) s += bv2[d] * brp[d];
      }
      b3[3072 + gid] = s;
    }
    return;
  }
  size_t i = ((size_t)blockIdx.x * 256 + threadIdx.x) * 4;
  const size_t NX = (size_t)4194304, NW = (size_t)1048576;
  const size_t BEND = NX + 4 * NW + 3072;
  const float* src;
  u16* dst;
  size_t o;
  if (i < NX) {
    src = x; dst = xA; o = i;
  } else if (i < NX + 3 * NW) {
    size_t j = i - NX;
    int sel = (int)(j >> 20);
    o = j & (NW - 1);
    src = sel == 0 ? Wq : sel == 1 ? Wv : Wk;
    dst = W3b + (size_t)sel * NW;
  } else if (i < NX + 4 * NW) {
    o = i - NX - 3 * NW;
    src = Wo; dst = Wob;
  } else if (i < BEND) {
    size_t j = i - NX - 4 * NW;
    int sel = (int)(j >> 10);
    o = j & 1023;
    src = sel == 0 ? bq : sel == 1 ? bv : bk;
    *reinterpret_cast<float4*>(b3 + j) = *reinterpret_cast<const float4*>(src + o);
    return;
  } else if (i < BEND + 262144) {
    // sinusoid table rows p in [0,256), pos = p-255 -> xA rows 4096..4351
    size_t j = i - BEND;
    int p = (int)(j >> 10);
    int ibase = (int)(j & 1023);
    ushort4 r;
    u16* rr = (u16*)&r;
#pragma unroll
    for (int c = 0; c < 4; ++c) {
      int idx = ibase + c;
      float ex = (float)(2 * (idx / 2)) * (1.0f / 1024.0f);
      float scale = exp2f(ex * -13.287712379549449f);  // 10000^-ex
      float angle = (float)(p - 255) * scale;
      rr[c] = f2bf((idx & 1) ? cosf(angle) : sinf(angle));
    }
    *reinterpret_cast<ushort4*>(xA + NX + j) = r;
    return;
  } else {
    return;
  }
  float4 v = *reinterpret_cast<const float4*>(src + o);
  ushort4 r;
  r.x = f2bf(v.x); r.y = f2bf(v.y); r.z = f2bf(v.z); r.w = f2bf(v.w);
  *reinterpret_cast<ushort4*>(dst + o) = r;
}

// -------- out-proj 128x128 bf16 MFMA GEMM, 3-buffer depth-2 pipeline ---------
// (unchanged from round 11)
__global__ __launch_bounds__(256) void gemm_k(
    const u16* __restrict__ A, const u16* __restrict__ W,
    const float* __restrict__ bias, float* __restrict__ Cv,
    int M, int N, int K, int mTiles, int nTiles) {
  const int xcd = blockIdx.x & 7;
  const int li  = blockIdx.x >> 3;
  const int r0   = (xcd * mTiles) >> 3;
  const int rcnt = (((xcd + 1) * mTiles) >> 3) - r0;
  if (li >= rcnt * nTiles) return;   // uniform early-out (padded grid)
  const int bm = (r0 + li % rcnt) * 128;
  const int bn = (li / rcnt) * 128;

  __shared__ u16 Alds[3][128 * 64];
  __shared__ u16 Blds[3][128 * 64];
  const int t = threadIdx.x, w = t >> 6, l = t & 63;
  const int l15 = l & 15, quad = l >> 4;
  const int wm = w >> 1, wn = w & 1;
  const int lrow8 = l >> 3;
  const int kslot = l & 7;
  const int NT = K >> 6;

  floatx4 acc[4][4] = {};

  auto stage = [&](int kt) {
    const int buf = kt % 3, k0 = kt << 6;
#pragma unroll
    for (int sg = 0; sg < 4; ++sg) {
      int mrow = sg * 32 + w * 8 + lrow8;
      int gk = (kslot ^ (mrow & 7)) << 3;
      GLL16(A + (size_t)(bm + mrow) * K + k0 + gk, Alds[buf] + (sg * 32 + w * 8) * 64);
      GLL16(W + (size_t)(bn + mrow) * K + k0 + gk, Blds[buf] + (sg * 32 + w * 8) * 64);
    }
  };

  stage(0); stage(1); stage(2);

  for (int kt = 0; kt < NT; ++kt) {
    if (kt + 2 < NT) {
      asm volatile("s_waitcnt vmcnt(16)" ::: "memory");
    } else if (kt + 1 < NT) {
      asm volatile("s_waitcnt vmcnt(8)" ::: "memory");
    } else {
      asm volatile("s_waitcnt vmcnt(0)" ::: "memory");
    }
    __builtin_amdgcn_s_barrier();
    __builtin_amdgcn_sched_barrier(0);
    const u16* AL = Alds[kt % 3];
    const u16* BL = Blds[kt % 3];
#pragma unroll
    for (int c = 0; c < 2; ++c) {
      bf16x8 af[4], bf[4];
#pragma unroll
      for (int mi = 0; mi < 4; ++mi) {
        int am = wm * 64 + mi * 16 + l15;
        af[mi] = *(const bf16x8*)(AL + am * 64 + (((c * 4 + quad) ^ (am & 7)) << 3));
      }
#pragma unroll
      for (int ni = 0; ni < 4; ++ni) {
        int an = wn * 64 + ni * 16 + l15;
        bf[ni] = *(const bf16x8*)(BL + an * 64 + (((c * 4 + quad) ^ (an & 7)) << 3));
      }
#pragma unroll
      for (int mi = 0; mi < 4; ++mi)
#pragma unroll
        for (int ni = 0; ni < 4; ++ni)
          acc[mi][ni] = MFMA16(af[mi], bf[ni], acc[mi][ni]);
    }
    __builtin_amdgcn_s_barrier();   // all reads of buf[kt%3] done (all waves)
    if (kt + 3 < NT) stage(kt + 3); // overwrites buf[kt%3] -- safe after barrier
  }

#pragma unroll
  for (int ni = 0; ni < 4; ++ni) {
    int col = bn + wn * 64 + ni * 16 + l15;
    float bv = bias[col];
#pragma unroll
    for (int mi = 0; mi < 4; ++mi) {
      int mrow = bm + wm * 64 + mi * 16 + quad * 4;
#pragma unroll
      for (int r = 0; r < 4; ++r) {
        Cv[(size_t)(mrow + r) * N + col] = acc[mi][ni][r] + bv;
      }
    }
  }
}

// ---- fused QVK 128x128 GEMM: A direct-from-global (L2-hot), B-only LDS ------
// Round-12 change. A's per-XCD working set (~4 slabs = 1 MB) is L2-resident
// under the bm-chunked swizzle -> staging A through LDS is pure overhead
// (lesson #7). A fragments load straight to VGPRs (16 lanes x 64B-per-row
// segments). LDS = B-only double buffer 32 KB -> with launch_bounds(256,3)
// occupancy rises to 3 blocks/CU (850 blocks ~ 1.1 rounds, tail gone) and
// 3 waves/SIMD of cross-block stall cover (m114). LDS read traffic halves.
// Counted vmcnt audit: per iter issue af(8) then stageB(kt+1)(4); at wait
// point outstanding = B(kt)(4,oldest)+af(8)+B(kt+1)(4) -> vmcnt(12) drains
// exactly B(kt). Edge kt=NT-1 (no stage): vmcnt(8). af regs tracked by
// compiler dependency waits. Post-compute barrier protects buf[kt&1] before
// stageB(kt+2) overwrites it next iter.
// Epilogue: two 64-row half-passes through a 32 KB fp32 bounce (same XOR-key
// family as the round-8-verified 157K-conflict epilogue).
__global__ __launch_bounds__(256, 3) void gemmqvk_k(
    const u16* __restrict__ A, const u16* __restrict__ W,
    const float* __restrict__ bias, u16* __restrict__ Cv,
    int K, float* __restrict__ utb, float* __restrict__ dtb,
    int mTiles, int nTiles) {
  // bijective XCD swizzle (m204)
  const int nwg = mTiles * nTiles;
  const int qq = nwg >> 3, rr8 = nwg & 7;
  const int xcd = blockIdx.x & 7;
  const int wgid = (xcd < rr8 ? xcd * (qq + 1) : rr8 * (qq + 1) + (xcd - rr8) * qq)
                   + (blockIdx.x >> 3);
  const int bm = (wgid / nTiles) * 128;
  const int bn = (wgid % nTiles) * 128;

  __shared__ u16 lds[2 * 8192];   // 32 KB: B-only double buffer (128x64 each)

  const int t = threadIdx.x, w = t >> 6, l = t & 63;
  const int l15 = l & 15, quad = l >> 4;
  const int wm = w >> 1, wn = w & 1;
  const int lrow8 = l >> 3;
  const int kslot = l & 7;
  const int NT = K >> 6;

  floatx4 acc[4][4] = {};

  auto stageB = [&](int kt) {
    const int k0 = kt << 6;
    u16* base = lds + (kt & 1) * 8192;
#pragma unroll
    for (int sg = 0; sg < 4; ++sg) {
      int mrow = sg * 32 + w * 8 + lrow8;
      int gk = (kslot ^ (mrow & 7)) << 3;
      GLL16(W + (size_t)(bn + mrow) * K + k0 + gk, base + (sg * 32 + w * 8) * 64);
    }
  };

  stageB(0);

  for (int kt = 0; kt < NT; ++kt) {
    const int k0 = kt << 6;
    // A fragments direct from global (L2-hot; no LDS round-trip)
    bf16x8 af[2][4];
#pragma unroll
    for (int c = 0; c < 2; ++c)
#pragma unroll
      for (int mi = 0; mi < 4; ++mi)
        af[c][mi] = *(const bf16x8*)(A +
            (size_t)(bm + wm * 64 + mi * 16 + l15) * K + k0 + c * 32 + quad * 8);
    if (kt + 1 < NT) {
      stageB(kt + 1);
      asm volatile("s_waitcnt vmcnt(12)" ::: "memory");  // drains B(kt)
    } else {
      asm volatile("s_waitcnt vmcnt(8)" ::: "memory");   // drains B(kt)
    }
    __builtin_amdgcn_s_barrier();
    __builtin_amdgcn_sched_barrier(0);
    const u16* BL = lds + (kt & 1) * 8192;
#pragma unroll
    for (int c = 0; c < 2; ++c) {
      bf16x8 bf[4];
#pragma unroll
      for (int ni = 0; ni < 4; ++ni) {
        int an = wn * 64 + ni * 16 + l15;
        bf[ni] = *(const bf16x8*)(BL + an * 64 + (((c * 4 + quad) ^ (an & 7)) << 3));
      }
#pragma unroll
      for (int mi = 0; mi < 4; ++mi)
#pragma unroll
        for (int ni = 0; ni < 4; ++ni)
          acc[mi][ni] = MFMA16(af[c][mi], bf[ni], acc[mi][ni]);
    }
    __builtin_amdgcn_s_barrier();   // all reads of buf[kt&1] done (all waves)
    // stageB(kt+2) next iter overwrites buf[kt&1] -- safe after this barrier
  }

  // ---- epilogue: two 64-row half-passes via 32 KB fp32 bounce ----
  float* fl = (float*)lds;   // 64 x 128 fp32 = 32 KB
  u16* VTp = Cv + (size_t)4194304;   // matsel==1 slot, transposed layout
#pragma unroll 1
  for (int hh = 0; hh < 2; ++hh) {
    __syncthreads();
    if (wm == hh) {
#pragma unroll
      for (int ni = 0; ni < 4; ++ni) {
        float bv = bias[bn + wn * 64 + ni * 16 + l15];
#pragma unroll
        for (int mi = 0; mi < 4; ++mi) {
#pragma unroll
          for (int r = 0; r < 4; ++r) {
            int lr = mi * 16 + quad * 4 + r;       // 0..63 within half
            int c  = wn * 64 + ni * 16 + l15;
            int key = ((r ^ quad) & 3) << 4;
            fl[lr * 128 + (c ^ key)] = acc[mi][ni][r] + bv;
          }
        }
      }
    }
    __syncthreads();
    if (bn >= 1024 && bn < 2048) {
      // V tile: emit transposed VT[bh][d][z]; bias already in fl.
      if (bm < 4096) {
        int bb = bm >> 8;
        int zb = bm & 128;               // z-offset of this tile within (b,h)
        int c = (w & 1) * 64 + l;        // lane owns one column 0..127
        int rbase = (w >> 1) * 32;       // rows 0-31 / 32-63 within half
        int col = bn + c;
        int hh2 = (col >> 6) & 15;
        u16* vpb = VTp + ((size_t)((bb << 4) + hh2) * 64 + (col & 63)) * 256 +
                   zb + hh * 64 + rbase;
#pragma unroll 1
        for (int pp = 0; pp < 4; ++pp) {
          int rb = rbase + pp * 8;
          u16 hv[8];
#pragma unroll
          for (int e = 0; e < 8; ++e) {
            int lr = rb + e;
            int key = ((lr & 3) ^ ((lr >> 2) & 3)) << 4;
            hv[e] = f2bf(fl[lr * 128 + (c ^ key)]);
          }
          *(ushort4*)(vpb + pp * 8) = *(ushort4*)&hv[0];
          *(ushort4*)(vpb + pp * 8 + 4) = *(ushort4*)&hv[4];
        }
      }
    } else {
      // wave w owns rows w*16 .. w*16+15 of the 64-row half
#pragma unroll 1
      for (int cc = 0; cc < 2; ++cc) {
        int col0 = bn + cc * 64;
#pragma unroll
        for (int rr = 0; rr < 4; ++rr) {
          int lr = w * 16 + rr * 4 + quad;
          int key = ((rr ^ quad) & 3) << 4;
          float4 v = *(const float4*)&fl[lr * 128 + ((cc * 64 + (l15 << 2)) ^ key)];
          int grow = bm + hh * 64 + lr;
          if (col0 < 3072) {
            ushort4 hvv;
            hvv.x = f2bf(v.x); hvv.y = f2bf(v.y); hvv.z = f2bf(v.z); hvv.w = f2bf(v.w);
            int matsel = col0 >> 10;       // 0=Q, 2=K (V handled above)
            int hh3 = (col0 >> 6) & 15;
            if (grow < 4096) {
              int bb = grow >> 8, ss = grow & 255;
              *(ushort4*)(Cv + (size_t)matsel * 4194304 +
                          ((size_t)(((bb << 4) + hh3) << 8) + ss) * 64 + (l15 << 2)) = hvv;
            } else if (matsel == 2) {      // table @ Wk^T -> RPKh
              int pp = grow - 4096;
              *(ushort4*)(Cv + (size_t)3 * 4194304 +
                          ((size_t)((hh3 << 8) + pp)) * 64 + (l15 << 2)) = hvv;
            }
          } else if (col0 < 3104) {        // cols 3072..3135 chunk: utb/dtb
#pragma unroll
            for (int e = 0; e < 4; ++e) {
              int col = col0 + (l15 << 2) + e;
              float vv = e == 0 ? v.x : e == 1 ? v.y : e == 2 ? v.z : v.w;
              if (col < 3088) {
                if (grow < 4096)
                  utb[((grow >> 8) * 16 + (col - 3072)) * 256 + (grow & 255)] = vv;
              } else if (col < 3104) {
                if (grow >= 4096)
                  dtb[(col - 3088) * 256 + (grow - 4096)] = vv;
              }
            }
          }
          // col0 >= 3136 (N-pad to 3200): discarded
        }
      }
    }
  }
}

// ---------------- fused attention v4: wave-autonomous, zero main-loop barriers ----
// (unchanged — verified)
__global__ __launch_bounds__(512, 2) void attn_k(
    const u16* __restrict__ Qh, const u16* __restrict__ Kh,
    const u16* __restrict__ VT, const u16* __restrict__ RPKh,
    const float* __restrict__ ut, const float* __restrict__ dt,
    u16* __restrict__ vw) {
  __shared__ float ScW[8][16 * 260];   // 133 KB wave-private score tiles
  __shared__ float Ut[256], Dt[256];

  const int bh = blockIdx.x;           // b*16 + h
  const int h = bh & 15;
  const int b = bh >> 4;
  const size_t bh256 = (size_t)bh << 8;

  const int t = threadIdx.x, w = t >> 6, l = t & 63;
  const int l15 = l & 15, quad = l >> 4;

  if (t < 256) Ut[t] = ut[bh256 + t];
  else         Dt[t - 256] = dt[((size_t)h << 8) + (t - 256)];
  __syncthreads();

  float* scw = &ScW[w][0];

#pragma unroll 1
  for (int sidx = 0; sidx < 2; ++sidx) {
    const int s = sidx ? (15 - w) : w;   // wave-uniform strip index 0..15
    const int rB = s << 4;               // absolute base row

    // strip-head loads: qa, K tile 0, RP task 0
    bf16x8 qa0, qa1;
    {
      const u16* qp = Qh + (bh256 + rB + l15) * 64 + quad * 8;
      qa0 = *(const bf16x8*)qp;
      qa1 = *(const bf16x8*)(qp + 32);
    }
    bf16x8 kA0, kA1, kB0, kB1, rA0, rA1, rB0, rB1;
    {
      const u16* kp = Kh + (bh256 + l15) * 64 + quad * 8;
      kA0 = *(const bf16x8*)kp;
      kA1 = *(const bf16x8*)(kp + 32);
      const u16* rp = RPKh + (((size_t)h << 8) + 240 - rB + l15) * 64 + quad * 8;
      rA0 = *(const bf16x8*)rp;
      rA1 = *(const bf16x8*)(rp + 32);
    }

    // ---- interleaved QK(j) / QR(j), 1-deep parity prefetch ----
#pragma unroll
    for (int j = 0; j < 16; ++j) {
      if (j > s) break;
      if (j + 1 <= s) {
        const u16* kp = Kh + (bh256 + ((j + 1) << 4) + l15) * 64 + quad * 8;
        const u16* rp = RPKh + (((size_t)h << 8) + 240 - rB + ((j + 1) << 4) + l15) * 64 + quad * 8;
        if ((j + 1) & 1) {
          kB0 = *(const bf16x8*)kp; kB1 = *(const bf16x8*)(kp + 32);
          rB0 = *(const bf16x8*)rp; rB1 = *(const bf16x8*)(rp + 32);
        } else {
          kA0 = *(const bf16x8*)kp; kA1 = *(const bf16x8*)(kp + 32);
          rA0 = *(const bf16x8*)rp; rA1 = *(const bf16x8*)(rp + 32);
        }
      }
      bf16x8 k0 = (j & 1) ? kB0 : kA0;   // j compile-time -> static select
      bf16x8 k1 = (j & 1) ? kB1 : kA1;
      bf16x8 r0 = (j & 1) ? rB0 : rA0;
      bf16x8 r1 = (j & 1) ? rB1 : rA1;
      // QK(j): C[row=4q+r][z=16j+l15]
      {
        floatx4 acc = {};
        acc = MFMA16(qa0, k0, acc);
        acc = MFMA16(qa1, k1, acc);
        float u = Ut[(j << 4) + l15];
#pragma unroll
        for (int r = 0; r < 4; ++r)
          scw[(4 * quad + r) * 260 + (j << 4) + l15] = acc[r] + u;
      }
      // QR(j): += at z = 16j + l15 + 4quad + r - 15
      {
        floatx4 acc = {};
        acc = MFMA16(qa0, r0, acc);
        acc = MFMA16(qa1, r1, acc);
        float dv = Dt[240 - rB + (j << 4) + l15];
#pragma unroll
        for (int r = 0; r < 4; ++r) {
          int z = (j << 4) + l15 + 4 * quad + r - 15;
          if (z >= 0)
            scw[(4 * quad + r) * 260 + z] += acc[r] + dv;
        }
      }
    }

    // ---- softmax pass 1: masked max (lane owns row l15) ----
    const int kcmax = s >> 1;
    const int Rabs = rB + l15;           // causal bound z <= Rabs
    float m = -1e30f;
#pragma unroll
    for (int kc = 0; kc < 8; ++kc) {
      if (kc > kcmax) break;
      const float* sp = scw + l15 * 260 + kc * 32 + quad * 8;
      floatx4 v0 = *(const floatx4*)sp;
      floatx4 v1 = *(const floatx4*)(sp + 4);
#pragma unroll
      for (int e = 0; e < 4; ++e) {
        int z = kc * 32 + quad * 8 + e;
        if (z <= Rabs) m = fmaxf(m, v0[e]);
        if (z + 4 <= Rabs) m = fmaxf(m, v1[e]);
      }
    }
    m = fmaxf(m, __shfl_xor(m, 16));
    m = fmaxf(m, __shfl_xor(m, 32));
    m *= kScale;

    // ---- pass 2: exp + PV (V^T fragments from global, 1-deep prefetch) ----
    floatx4 oacc[4] = {};
    float sum = 0.f;
    bf16x8 vA[4], vB[4];
    {
      const u16* vp = VT + ((size_t)bh * 64 + l15) * 256 + quad * 8;
#pragma unroll
      for (int nt = 0; nt < 4; ++nt)
        vA[nt] = *(const bf16x8*)(vp + (size_t)nt * 16 * 256);
    }
#pragma unroll
    for (int kc = 0; kc < 8; ++kc) {
      if (kc > kcmax) break;
      if (kc + 1 <= kcmax) {
        const u16* vp = VT + ((size_t)bh * 64 + l15) * 256 + (kc + 1) * 32 + quad * 8;
        if ((kc + 1) & 1) {
#pragma unroll
          for (int nt = 0; nt < 4; ++nt)
            vB[nt] = *(const bf16x8*)(vp + (size_t)nt * 16 * 256);
        } else {
#pragma unroll
          for (int nt = 0; nt < 4; ++nt)
            vA[nt] = *(const bf16x8*)(vp + (size_t)nt * 16 * 256);
        }
      }
      const float* sp = scw + l15 * 260 + kc * 32 + quad * 8;
      floatx4 v0 = *(const floatx4*)sp;
      floatx4 v1 = *(const floatx4*)(sp + 4);
      bf16x8 pa;
#pragma unroll
      for (int e = 0; e < 4; ++e) {
        int z = kc * 32 + quad * 8 + e;
        float p0 = (z <= Rabs) ? __expf(v0[e] * kScale - m) : 0.f;
        float p1 = (z + 4 <= Rabs) ? __expf(v1[e] * kScale - m) : 0.f;
        sum += p0 + p1;
        pa[e] = (short)f2bf(p0);
        pa[e + 4] = (short)f2bf(p1);
      }
#pragma unroll
      for (int nt = 0; nt < 4; ++nt)
        oacc[nt] = MFMA16(pa, (kc & 1) ? vB[nt] : vA[nt], oacc[nt]);
    }
    sum += __shfl_xor(sum, 16);
    sum += __shfl_xor(sum, 32);
    float rinv = 1.f / sum;

    // ---- store: row = rB + 4quad + r; rinv transposed via shfl ----
#pragma unroll
    for (int r = 0; r < 4; ++r) {
      float rs = __shfl(rinv, 4 * quad + r);
      int row = rB + 4 * quad + r;
#pragma unroll
      for (int nt = 0; nt < 4; ++nt)
        vw[(size_t)(b * 256 + row) * 1024 + h * 64 + nt * 16 + l15] =
            f2bf(oacc[nt][r] * rs);
    }
  }
}

extern "C" void kernel_launch(void* const* d_in, const int* in_sizes, int n_in,
                              void* d_out, int out_size, void* d_ws, size_t ws_size,
                              hipStream_t stream) {
  const float* x  = (const float*)d_in[0];
  const float* Wq = (const float*)d_in[1];
  const float* bq = (const float*)d_in[2];
  const float* Wk = (const float*)d_in[3];
  const float* bk = (const float*)d_in[4];
  const float* Wv = (const float*)d_in[5];
  const float* bv = (const float*)d_in[6];
  const float* Wr = (const float*)d_in[7];
  const float* br = (const float*)d_in[8];
  const float* ub = (const float*)d_in[9];
  const float* vb = (const float*)d_in[10];
  const float* Wo = (const float*)d_in[11];
  const float* bo = (const float*)d_in[12];
  float* out = (float*)d_out;

  char* base = (char*)d_ws;
  size_t off = 0;
  auto alloc = [&](size_t bytes) {
    void* p = base + off;
    off += (bytes + 255) & ~(size_t)255;
    return p;
  };

  const size_t MAT = (size_t)4194304;  // 4096*1024
  u16*   xA    = (u16*)alloc((size_t)4352 * 1024 * 2);       // [x ; table]
  u16*   W3b   = (u16*)alloc((size_t)3328 * 1024 * 2);       // [Wq;Wv;Wk;UV;pad]
  u16*   Wob   = (u16*)alloc((size_t)1024 * 1024 * 2);
  float* b3    = (float*)alloc((size_t)3328 * 4);
  u16*   Ph    = (u16*)alloc((3 * MAT + 262144) * 2);        // Qh,VT,Kh,RPKh
  float* utb   = (float*)alloc((size_t)65536 * 4);
  float* dtb   = (float*)alloc((size_t)4096 * 4);
  u16*   vwb   = (u16*)alloc((size_t)4096 * 1024 * 2);

  u16* Qh   = Ph;
  u16* VTb  = Ph + MAT;       // transposed V: [bh][d][z]
  u16* Kh   = Ph + 2 * MAT;
  u16* RPKh = Ph + 3 * MAT;

  // pack + table + uv-fold merged: 8451 pack blocks + 128 fold blocks
  pack_k<<<dim3(8579), dim3(256), 0, stream>>>(x, Wq, Wk, Wv, Wo, bq, bk, bv,
                                               Wr, br, ub, vb,
                                               xA, W3b, Wob, b3);

  // fused Q|V^T|K + relpos-K + ut/dt projections: 4352 x 3200(pad) x 1024
  // 128^2 tiles: mTiles=34, nTiles=25 -> 850 blocks, 3 blocks/CU co-resident
  gemmqvk_k<<<dim3(850), dim3(256), 0, stream>>>(xA, W3b, b3, Ph,
                                                 1024, utb, dtb, 34, 25);

  // fused attention: one block per (b,h), wave-autonomous strips
  attn_k<<<dim3(256), dim3(512), 0, stream>>>(Qh, Kh, VTb, RPKh, utb, dtb, vwb);

  // output projection: 4096 x 1024 x 1024, fp32 out, 3-buffer depth-2 pipeline
  gemm_k<<<dim3(256), dim3(256), 0, stream>>>(vwb, Wob, bo, out,
                                              4096, 1024, 1024, 32, 8);
}